// Round 1
// baseline (230.058 us; speedup 1.0000x reference)
//
#include <hip/hip_runtime.h>

// Problem: B=32, S=2048, I=128, H=512, O=64, R=1, ALPHA=0.1
// Rank-1 decomposition: the entire recurrent state reduces to scalar v_t per batch.
//   u[b,t]  = x[b,t,:] . input_receptive                       (K1)
//   v_t     = 0.9 v_{t-1} + 0.1 * sum_h rr[h]*relu(v_{t-1}*rp[h] + u_t*ipj[h])   (K2, chunked+warmup)
//   w_t[o]  = sum_h W[o,h]*relu(v_{t-1}*rp[h] + u_t*ipj[h])    (K3, bf16 MFMA GEMM)
//   y_t     = 0.9 y_{t-1} + 0.1 w_t ; out = y + bias           (K4, chunked+warmup)
// Warm-up W=96: contraction factor ~0.9 per step -> truncation error ~4e-5 * |state| << 1.9e-3.

#define B_ 32
#define S_ 2048
#define I_ 128
#define H_ 512
#define O_ 64

typedef __attribute__((ext_vector_type(8))) short bf16x8;
typedef __attribute__((ext_vector_type(4))) float f32x4;

__device__ __forceinline__ unsigned short f2bf(float f) {
  // RNE float->bf16 (no NaN/Inf in this workload)
  unsigned int b = __float_as_uint(f);
  b += 0x7FFFu + ((b >> 16) & 1u);
  return (unsigned short)(b >> 16);
}

// ---------------- K1: u[row] = x[row,:128] . input_receptive, one wave per row
__global__ __launch_bounds__(256) void k_u(const float* __restrict__ x,
                                           const float* __restrict__ irc,
                                           float* __restrict__ u) {
  int gid = blockIdx.x * 256 + threadIdx.x;
  int row = gid >> 6;          // 0 .. B*S-1
  int lane = threadIdx.x & 63;
  const float2* xr = (const float2*)(x + (size_t)row * I_);
  float2 xv = xr[lane];
  float2 cv = ((const float2*)irc)[lane];
  float s = xv.x * cv.x + xv.y * cv.y;
  #pragma unroll
  for (int off = 32; off; off >>= 1) s += __shfl_xor(s, off, 64);
  if (lane == 0) u[row] = s;
}

// ---------------- K0: pack W^T into MFMA B-fragment order (bf16)
// B-frag for 16x16x32: lane l holds B[k = (l>>4)*8 + j][n = l&15], j=0..7
// BF[((kt*4+ot)*64 + lane)*8 + j] = bf16( W[(ot*16 + (lane&15))*512 + kt*32 + (lane>>4)*8 + j] )
__global__ __launch_bounds__(256) void k_bf(const float* __restrict__ W,
                                            unsigned short* __restrict__ BF) {
  int idx = blockIdx.x * 256 + threadIdx.x;    // 0 .. 32767
  int j = idx & 7;
  int lane = (idx >> 3) & 63;
  int ot = (idx >> 9) & 3;
  int kt = idx >> 11;                          // 0..15
  int o = ot * 16 + (lane & 15);
  int h = kt * 32 + (lane >> 4) * 8 + j;
  BF[idx] = f2bf(W[o * H_ + h]);
}

// ---------------- K2: chunked v-scan with warm-up. One wave per (b, chunk of 64 t), warm-up 96.
// Stores V[b][t] = v_{t-1} (state entering step t).
__global__ __launch_bounds__(64) void k_vscan(const float* __restrict__ u,
                                              const float* __restrict__ rp,
                                              const float* __restrict__ ipj,
                                              const float* __restrict__ rr,
                                              float* __restrict__ V) {
  int b = blockIdx.x;       // 0..31
  int c = blockIdx.y;       // 0..31 chunks of 64
  int lane = threadIdx.x;   // 0..63
  float rpv[8], ipv[8], rrv[8];
  #pragma unroll
  for (int k = 0; k < 8; k++) {
    int h = lane + 64 * k;
    rpv[k] = rp[h]; ipv[k] = ipj[h]; rrv[k] = rr[h];
  }
  int real0 = c * 64;
  int t0 = real0 - 96; if (t0 < 0) t0 = 0;   // c==0 starts exact at t=0
  int tend = real0 + 64;
  const float* ub = u + b * S_;
  float v = 0.f;
  for (int t = t0; t < tend; t++) {
    if (t >= real0 && lane == 0) V[b * S_ + t] = v;  // v_{t-1}
    float ut = ub[t];
    float s = 0.f;
    #pragma unroll
    for (int k = 0; k < 8; k++) {
      float p = fmaf(v, rpv[k], ut * ipv[k]);
      p = fmaxf(p, 0.f);
      s = fmaf(rrv[k], p, s);
    }
    #pragma unroll
    for (int off = 32; off; off >>= 1) s += __shfl_xor(s, off, 64);
    v = fmaf(0.9f, v, 0.1f * s);
  }
}

// ---------------- K3: w[b,t,o] = sum_h W[o,h]*relu(V*rp + u*ipj) via 16x16x32 bf16 MFMA.
// Block = 4 waves, one (b, 64-t tile); wave handles 16-t strip x 64 o. A generated in-register.
__global__ __launch_bounds__(256) void k_w(const float* __restrict__ V,
                                           const float* __restrict__ u,
                                           const float* __restrict__ rp,
                                           const float* __restrict__ ipj,
                                           const unsigned short* __restrict__ BF,
                                           unsigned short* __restrict__ wbuf) {
  int b = blockIdx.x;          // 32
  int tb = blockIdx.y;         // 32 tiles of 64 t
  int wv = threadIdx.x >> 6;   // 0..3
  int lane = threadIdx.x & 63;
  int tl = lane & 15, quad = lane >> 4;
  int t = tb * 64 + wv * 16 + tl;           // A-operand row (m = lane&15)
  float Vt = V[b * S_ + t];
  float ut = u[b * S_ + t];
  f32x4 acc[4] = {};
  for (int kt = 0; kt < 16; kt++) {
    int hbase = kt * 32 + quad * 8;         // A: k = quad*8 + j
    f32x4 rp4a = *(const f32x4*)(rp + hbase);
    f32x4 rp4b = *(const f32x4*)(rp + hbase + 4);
    f32x4 ip4a = *(const f32x4*)(ipj + hbase);
    f32x4 ip4b = *(const f32x4*)(ipj + hbase + 4);
    bf16x8 a;
    #pragma unroll
    for (int j = 0; j < 4; j++) {
      float r = fmaxf(fmaf(Vt, rp4a[j], ut * ip4a[j]), 0.f);
      a[j] = (short)f2bf(r);
    }
    #pragma unroll
    for (int j = 0; j < 4; j++) {
      float r = fmaxf(fmaf(Vt, rp4b[j], ut * ip4b[j]), 0.f);
      a[4 + j] = (short)f2bf(r);
    }
    #pragma unroll
    for (int ot = 0; ot < 4; ot++) {
      bf16x8 bfrag = *(const bf16x8*)(BF + (((kt * 4 + ot) * 64 + lane) << 3));
      acc[ot] = __builtin_amdgcn_mfma_f32_16x16x32_bf16(a, bfrag, acc[ot], 0, 0, 0);
    }
  }
  // C/D layout: col = lane&15 (o within tile), row = quad*4 + r (t within strip)
  int trow_base = tb * 64 + wv * 16 + quad * 4;
  #pragma unroll
  for (int r = 0; r < 4; r++) {
    int tw = trow_base + r;
    #pragma unroll
    for (int ot = 0; ot < 4; ot++) {
      wbuf[((size_t)(b * S_ + tw)) * O_ + ot * 16 + tl] = f2bf(acc[ot][r]);
    }
  }
}

// ---------------- K4: y-scan, chunked (128 real + 96 warm-up), thread per (b, chunk, o).
__global__ __launch_bounds__(256) void k_yscan(const unsigned short* __restrict__ wbuf,
                                               const float* __restrict__ bias,
                                               float* __restrict__ out) {
  int id = blockIdx.x * 256 + threadIdx.x;   // 0 .. 32767
  int o = id & 63;
  int g = id >> 6;
  int c = g & 15;        // 16 chunks of 128
  int b = g >> 4;
  int real0 = c * 128;
  int t0 = real0 - 96; if (t0 < 0) t0 = 0;
  float y = 0.f;
  float bo = bias[o];
  const unsigned short* wb = wbuf + (size_t)(b * S_) * O_ + o;
  float* ob = out + (size_t)(b * S_) * O_ + o;
  for (int t = t0; t < real0 + 128; t++) {
    float wv = __uint_as_float(((unsigned)wb[(size_t)t * O_]) << 16);
    y = fmaf(0.9f, y, 0.1f * wv);
    if (t >= real0) ob[(size_t)t * O_] = y + bo;
  }
}

extern "C" void kernel_launch(void* const* d_in, const int* in_sizes, int n_in,
                              void* d_out, int out_size, void* d_ws, size_t ws_size,
                              hipStream_t stream) {
  const float* x   = (const float*)d_in[0];   // [B,S,I]
  const float* ipj = (const float*)d_in[1];   // input_projective [H]
  const float* irc = (const float*)d_in[2];   // input_receptive [I]
  const float* rpj = (const float*)d_in[3];   // rec_projective [H]
  const float* rrc = (const float*)d_in[4];   // rec_receptive [H]
  const float* Wr  = (const float*)d_in[5];   // readout_w [O,H]
  const float* br  = (const float*)d_in[6];   // readout_b [O]
  float* out = (float*)d_out;

  char* ws = (char*)d_ws;
  float* u            = (float*)(ws);                     // 256 KB
  float* V            = (float*)(ws + (256 << 10));       // 256 KB
  unsigned short* BF  = (unsigned short*)(ws + (512 << 10)); // 64 KB
  unsigned short* wbf = (unsigned short*)(ws + (1024 << 10)); // 8 MB (bf16 w)

  k_u<<<(B_ * S_) / 4, 256, 0, stream>>>(x, irc, u);
  k_bf<<<128, 256, 0, stream>>>(Wr, BF);
  k_vscan<<<dim3(B_, 32), 64, 0, stream>>>(u, rpj, ipj, rrc, V);
  k_w<<<dim3(B_, 32), 256, 0, stream>>>(V, u, rpj, ipj, BF, wbf);
  k_yscan<<<128, 256, 0, stream>>>(wbf, br, out);
}

// Round 2
// 161.627 us; speedup vs baseline: 1.4234x; 1.4234x over previous
//
#include <hip/hip_runtime.h>

// Problem: B=32, S=2048, I=128, H=512, O=64, R=1, ALPHA=0.1
// Rank-1 decomposition: recurrent state reduces to scalar v_t per batch.
//   u[b,t]  = x[b,t,:] . input_receptive                       (K1)
//   v_t     = 0.9 v_{t-1} + 0.1 * sum_h rr[h]*relu(v_{t-1}*rp[h] + u_t*ipj[h])   (K2)
//   w_t[o]  = sum_h W[o,h]*relu(v_{t-1}*rp[h] + u_t*ipj[h])    (K3, bf16 MFMA)
//   y_t     = 0.9 y_{t-1} + 0.1 w_t ; out = y + bias           (K4)
// Chunk-parallel scans with 96-step warm-up (0.9^96 ~ 4e-5 truncation).

#define B_ 32
#define S_ 2048
#define I_ 128
#define H_ 512
#define O_ 64

typedef __attribute__((ext_vector_type(8))) short bf16x8;
typedef __attribute__((ext_vector_type(4))) float f32x4;

__device__ __forceinline__ unsigned short f2bf(float f) {
  unsigned int b = __float_as_uint(f);
  b += 0x7FFFu + ((b >> 16) & 1u);
  return (unsigned short)(b >> 16);
}
__device__ __forceinline__ float bf2f(unsigned short s) {
  return __uint_as_float(((unsigned)s) << 16);
}

// ---------------- K1: u[row] = x[row,:128] . input_receptive, one wave per row
__global__ __launch_bounds__(256) void k_u(const float* __restrict__ x,
                                           const float* __restrict__ irc,
                                           float* __restrict__ u) {
  int gid = blockIdx.x * 256 + threadIdx.x;
  int row = gid >> 6;
  int lane = threadIdx.x & 63;
  const float2* xr = (const float2*)(x + (size_t)row * I_);
  float2 xv = xr[lane];
  float2 cv = ((const float2*)irc)[lane];
  float s = xv.x * cv.x + xv.y * cv.y;
  #pragma unroll
  for (int off = 32; off; off >>= 1) s += __shfl_xor(s, off, 64);
  if (lane == 0) u[row] = s;
}

// ---------------- K0: pack W^T into MFMA B-fragment order (bf16)
__global__ __launch_bounds__(256) void k_bf(const float* __restrict__ W,
                                            unsigned short* __restrict__ BF) {
  int idx = blockIdx.x * 256 + threadIdx.x;
  int j = idx & 7;
  int lane = (idx >> 3) & 63;
  int ot = (idx >> 9) & 3;
  int kt = idx >> 11;
  int o = ot * 16 + (lane & 15);
  int h = kt * 32 + (lane >> 4) * 8 + j;
  BF[idx] = f2bf(W[o * H_ + h]);
}

// DPP row-rotate add: after ror 1,2,4,8 every lane holds its 16-lane row sum.
#define ROR_ADD(s, CTRL) \
  s += __int_as_float(__builtin_amdgcn_update_dpp(0, __float_as_int(s), CTRL, 0xF, 0xF, true))

// ---------------- K2: chunked v-scan, warm-up 96. One wave per (b, 64-t chunk).
__global__ __launch_bounds__(64) void k_vscan(const float* __restrict__ u,
                                              const float* __restrict__ rp,
                                              const float* __restrict__ ipj,
                                              const float* __restrict__ rr,
                                              float* __restrict__ V) {
  int b = blockIdx.x;
  int c = blockIdx.y;
  int lane = threadIdx.x;
  float rpv[8], ipv[8], rrv[8];
  #pragma unroll
  for (int k = 0; k < 8; k++) {
    int h = lane + 64 * k;
    rpv[k] = rp[h]; ipv[k] = ipj[h]; rrv[k] = rr[h];
  }
  int real0 = c * 64;
  int t0 = real0 - 96; if (t0 < 0) t0 = 0;
  int tend = real0 + 64;
  const float* ub = u + b * S_;
  float v = 0.f;
  for (int t = t0; t < tend; t++) {
    if (t >= real0 && lane == 0) V[b * S_ + t] = v;  // v_{t-1}
    float ut = ub[t];
    float s = 0.f;
    #pragma unroll
    for (int k = 0; k < 8; k++) {
      float p = fmaf(v, rpv[k], ut * ipv[k]);
      s = fmaf(rrv[k], fmaxf(p, 0.f), s);
    }
    // row (16-lane) rotate-reduce on the VALU pipe, then 4 readlanes -> total
    ROR_ADD(s, 0x121); ROR_ADD(s, 0x122); ROR_ADD(s, 0x124); ROR_ADD(s, 0x128);
    float tot = __int_as_float(__builtin_amdgcn_readlane(__float_as_int(s), 0)) +
                __int_as_float(__builtin_amdgcn_readlane(__float_as_int(s), 16)) +
                __int_as_float(__builtin_amdgcn_readlane(__float_as_int(s), 32)) +
                __int_as_float(__builtin_amdgcn_readlane(__float_as_int(s), 48));
    v = fmaf(0.9f, v, 0.1f * tot);
  }
}

// ---------------- K3: w[b,t,o] via 16x16x32 bf16 MFMA, A generated in-register.
__global__ __launch_bounds__(256) void k_w(const float* __restrict__ V,
                                           const float* __restrict__ u,
                                           const float* __restrict__ rp,
                                           const float* __restrict__ ipj,
                                           const unsigned short* __restrict__ BF,
                                           unsigned short* __restrict__ wbuf) {
  int b = blockIdx.x;
  int tb = blockIdx.y;
  int wv = threadIdx.x >> 6;
  int lane = threadIdx.x & 63;
  int tl = lane & 15, quad = lane >> 4;
  int t = tb * 64 + wv * 16 + tl;
  float Vt = V[b * S_ + t];
  float ut = u[b * S_ + t];
  f32x4 acc[4] = {};
  for (int kt = 0; kt < 16; kt++) {
    int hbase = kt * 32 + quad * 8;
    f32x4 rp4a = *(const f32x4*)(rp + hbase);
    f32x4 rp4b = *(const f32x4*)(rp + hbase + 4);
    f32x4 ip4a = *(const f32x4*)(ipj + hbase);
    f32x4 ip4b = *(const f32x4*)(ipj + hbase + 4);
    bf16x8 a;
    #pragma unroll
    for (int j = 0; j < 4; j++) {
      float r = fmaxf(fmaf(Vt, rp4a[j], ut * ip4a[j]), 0.f);
      a[j] = (short)f2bf(r);
    }
    #pragma unroll
    for (int j = 0; j < 4; j++) {
      float r = fmaxf(fmaf(Vt, rp4b[j], ut * ip4b[j]), 0.f);
      a[4 + j] = (short)f2bf(r);
    }
    #pragma unroll
    for (int ot = 0; ot < 4; ot++) {
      bf16x8 bfrag = *(const bf16x8*)(BF + (((kt * 4 + ot) * 64 + lane) << 3));
      acc[ot] = __builtin_amdgcn_mfma_f32_16x16x32_bf16(a, bfrag, acc[ot], 0, 0, 0);
    }
  }
  int trow_base = tb * 64 + wv * 16 + quad * 4;
  #pragma unroll
  for (int r = 0; r < 4; r++) {
    int tw = trow_base + r;
    #pragma unroll
    for (int ot = 0; ot < 4; ot++) {
      wbuf[((size_t)(b * S_ + tw)) * O_ + ot * 16 + tl] = f2bf(acc[ot][r]);
    }
  }
}

// ---------------- K4: y-scan. One wave per (b, 64-t chunk); stage 160x64 bf16
// window into LDS with pipelined uint4 copies, then scan from LDS (lane = o).
__global__ __launch_bounds__(64) void k_yscan(const unsigned short* __restrict__ wbuf,
                                              const float* __restrict__ bias,
                                              float* __restrict__ out) {
  __shared__ unsigned short wtile[160 * 64];  // 20 KB
  int b = blockIdx.x;
  int c = blockIdx.y;
  int lane = threadIdx.x;
  int real0 = c * 64;
  int t0 = real0 - 96; if (t0 < 0) t0 = 0;
  int n = real0 + 64 - t0;        // <= 160
  int warm = real0 - t0;

  const uint4* src = (const uint4*)(wbuf + (size_t)(b * S_ + t0) * O_);
  uint4* dst = (uint4*)wtile;
  int total16 = n * 8;            // 16B units per 64-o row: 128B -> 8
  for (int i = lane; i < total16; i += 64) dst[i] = src[i];
  __syncthreads();

  float y = 0.f;
  float bo = bias[lane];
  float* ob = out + ((size_t)(b * S_ + real0)) * O_ + lane;
  const unsigned short* wl = wtile + lane;
  for (int t = 0; t < n; t++) {
    float wv = bf2f(wl[t * 64]);
    y = fmaf(0.9f, y, 0.1f * wv);
    if (t >= warm) ob[(size_t)(t - warm) * O_] = y + bo;
  }
}

extern "C" void kernel_launch(void* const* d_in, const int* in_sizes, int n_in,
                              void* d_out, int out_size, void* d_ws, size_t ws_size,
                              hipStream_t stream) {
  const float* x   = (const float*)d_in[0];
  const float* ipj = (const float*)d_in[1];
  const float* irc = (const float*)d_in[2];
  const float* rpj = (const float*)d_in[3];
  const float* rrc = (const float*)d_in[4];
  const float* Wr  = (const float*)d_in[5];
  const float* br  = (const float*)d_in[6];
  float* out = (float*)d_out;

  char* ws = (char*)d_ws;
  float* u            = (float*)(ws);                        // 256 KB
  float* V            = (float*)(ws + (256 << 10));          // 256 KB
  unsigned short* BF  = (unsigned short*)(ws + (512 << 10)); // 64 KB
  unsigned short* wbf = (unsigned short*)(ws + (1024 << 10)); // 8 MB

  k_u<<<(B_ * S_) / 4, 256, 0, stream>>>(x, irc, u);
  k_bf<<<128, 256, 0, stream>>>(Wr, BF);
  k_vscan<<<dim3(B_, 32), 64, 0, stream>>>(u, rpj, ipj, rrc, V);
  k_w<<<dim3(B_, 32), 256, 0, stream>>>(V, u, rpj, ipj, BF, wbf);
  k_yscan<<<dim3(B_, 32), 64, 0, stream>>>(wbf, br, out);
}

// Round 3
// 150.809 us; speedup vs baseline: 1.5255x; 1.0717x over previous
//
#include <hip/hip_runtime.h>

// B=32, S=2048, I=128, H=512, O=64, R=1, ALPHA=0.1  (rank-1 scalar-state RNN)
//   u[b,t]  = x[b,t,:] . input_receptive                       (k_ubf)
//   v_t     = 0.9 v + 0.1 sum_h rr[h]*relu(v*rp[h] + u_t*ipj[h])   (k_vscan)
//   w_t[o]  = sum_h W[o,h]*relu(v*rp[h] + u_t*ipj[h])          (k_w, bf16 MFMA)
//   y_t     = 0.9 y + 0.1 w_t ; out = y + bias                 (k_yscan)
// Chunk-parallel scans, 96-step warm-up (0.9^96 ~ 4e-5 truncation).

#define B_ 32
#define S_ 2048
#define I_ 128
#define H_ 512
#define O_ 64

typedef __attribute__((ext_vector_type(8))) short bf16x8;
typedef __attribute__((ext_vector_type(4))) float f32x4;

__device__ __forceinline__ unsigned short f2bf(float f) {
  unsigned int b = __float_as_uint(f);
  b += 0x7FFFu + ((b >> 16) & 1u);
  return (unsigned short)(b >> 16);
}
__device__ __forceinline__ float bf2f(unsigned short s) {
  return __uint_as_float(((unsigned)s) << 16);
}
// pack two floats -> bf16x2 (round-to-nearest, cheap)
__device__ __forceinline__ unsigned pack_bf(float lo, float hi) {
  unsigned a = (__float_as_uint(lo) + 0x8000u) >> 16;
  unsigned b = (__float_as_uint(hi) + 0x8000u) & 0xFFFF0000u;
  return a | b;
}

// ---------------- k_ubf: u[row] = x[row,:].irc (blocks 0..16383); BF pack (last 128 blocks)
__global__ __launch_bounds__(256) void k_ubf(const float* __restrict__ x,
                                             const float* __restrict__ irc,
                                             const float* __restrict__ W,
                                             float* __restrict__ u,
                                             unsigned short* __restrict__ BF) {
  if (blockIdx.x >= (B_ * S_ / 4)) {
    // W^T -> MFMA B-frag order: BF[((kt*4+ot)*64+lane)*8+j] = W[(ot*16+(lane&15))*H + kt*32+(lane>>4)*8+j]
    int idx = (blockIdx.x - B_ * S_ / 4) * 256 + threadIdx.x;   // 0..32767
    int j = idx & 7;
    int lane = (idx >> 3) & 63;
    int ot = (idx >> 9) & 3;
    int kt = idx >> 11;
    int o = ot * 16 + (lane & 15);
    int h = kt * 32 + (lane >> 4) * 8 + j;
    BF[idx] = f2bf(W[o * H_ + h]);
    return;
  }
  int gid = blockIdx.x * 256 + threadIdx.x;
  int row = gid >> 6;
  int lane = threadIdx.x & 63;
  const float2* xr = (const float2*)(x + (size_t)row * I_);
  float2 xv = xr[lane];
  float2 cv = ((const float2*)irc)[lane];
  float s = xv.x * cv.x + xv.y * cv.y;
  #pragma unroll
  for (int off = 32; off; off >>= 1) s += __shfl_xor(s, off, 64);
  if (lane == 0) u[row] = s;
}

// DPP row-rotate add: after ror 1,2,4,8 every lane holds its 16-lane row sum.
#define ROR_ADD(s, CTRL) \
  s += __int_as_float(__builtin_amdgcn_update_dpp(0, __float_as_int(s), CTRL, 0xF, 0xF, true))

// ---------------- k_vscan: chunks of 32 t, uniform 128-step loop (96 warm-up).
// Steps with t<0 use u=0 which keeps v==0, so all chunks run identical code.
__global__ __launch_bounds__(64) void k_vscan(const float* __restrict__ u,
                                              const float* __restrict__ rp,
                                              const float* __restrict__ ipj,
                                              const float* __restrict__ rr,
                                              float* __restrict__ V) {
  __shared__ float su[128];
  int b = blockIdx.x;        // 0..31
  int c = blockIdx.y;        // 0..63, real0 = 32*c
  int lane = threadIdx.x;
  float rpv[8], ipv[8], rrv[8];
  #pragma unroll
  for (int k = 0; k < 8; k++) {
    int h = lane + 64 * k;
    rpv[k] = rp[h]; ipv[k] = ipj[h]; rrv[k] = rr[h];
  }
  int real0 = c * 32;
  int t0 = real0 - 96;
  const float* ub = u + b * S_;
  int ta = t0 + lane, tb = t0 + 64 + lane;
  su[lane]      = (ta >= 0) ? ub[ta] : 0.f;
  su[lane + 64] = (tb >= 0) ? ub[tb] : 0.f;
  __syncthreads();
  float v = 0.f;
  float* Vb = V + b * S_ + real0;
  #pragma unroll 8
  for (int i = 0; i < 128; i++) {
    if (i >= 96 && lane == 0) Vb[i - 96] = v;   // V[b][t] = v entering step t
    float ut = su[i];
    float q0 = fmaxf(fmaf(v, rpv[0], ut * ipv[0]), 0.f) * rrv[0];
    float q1 = fmaxf(fmaf(v, rpv[1], ut * ipv[1]), 0.f) * rrv[1];
    float q2 = fmaxf(fmaf(v, rpv[2], ut * ipv[2]), 0.f) * rrv[2];
    float q3 = fmaxf(fmaf(v, rpv[3], ut * ipv[3]), 0.f) * rrv[3];
    float q4 = fmaxf(fmaf(v, rpv[4], ut * ipv[4]), 0.f) * rrv[4];
    float q5 = fmaxf(fmaf(v, rpv[5], ut * ipv[5]), 0.f) * rrv[5];
    float q6 = fmaxf(fmaf(v, rpv[6], ut * ipv[6]), 0.f) * rrv[6];
    float q7 = fmaxf(fmaf(v, rpv[7], ut * ipv[7]), 0.f) * rrv[7];
    float s = ((q0 + q1) + (q2 + q3)) + ((q4 + q5) + (q6 + q7));
    ROR_ADD(s, 0x121); ROR_ADD(s, 0x122); ROR_ADD(s, 0x124); ROR_ADD(s, 0x128);
    float tot = __int_as_float(__builtin_amdgcn_readlane(__float_as_int(s), 0)) +
                __int_as_float(__builtin_amdgcn_readlane(__float_as_int(s), 16)) +
                __int_as_float(__builtin_amdgcn_readlane(__float_as_int(s), 32)) +
                __int_as_float(__builtin_amdgcn_readlane(__float_as_int(s), 48));
    v = fmaf(0.9f, v, 0.1f * tot);
  }
}

// ---------------- k_w: w = relu(V*rp + u*ipj) @ W^T via 16x16x32 bf16 MFMA.
// 256 WGs (1/CU), 4 waves; wave owns 64 rows (4 m-tiles). BF staged to LDS once;
// kt-outer loop keeps that kt's 4 B-frags in registers -> each frag read once/wave.
__global__ __launch_bounds__(256) void k_w(const float* __restrict__ V,
                                           const float* __restrict__ u,
                                           const float* __restrict__ rp,
                                           const float* __restrict__ ipj,
                                           const unsigned short* __restrict__ BF,
                                           unsigned short* __restrict__ wbuf) {
  __shared__ unsigned short sBF[32768];   // 64 KB
  {
    const uint4* s = (const uint4*)BF;
    uint4* d = (uint4*)sBF;
    int tid = threadIdx.x;
    #pragma unroll
    for (int i = 0; i < 16; i++) d[tid + 256 * i] = s[tid + 256 * i];
  }
  __syncthreads();
  int wv = threadIdx.x >> 6, lane = threadIdx.x & 63;
  int tl = lane & 15, quad = lane >> 4;
  int row0 = blockIdx.x * 256 + wv * 64;
  float Vr[4], ur[4];
  #pragma unroll
  for (int mt = 0; mt < 4; mt++) {
    Vr[mt] = V[row0 + mt * 16 + tl];
    ur[mt] = u[row0 + mt * 16 + tl];
  }
  f32x4 acc[4][4] = {};   // [mt][ot]
  #pragma unroll 4
  for (int kt = 0; kt < 16; kt++) {
    int hbase = kt * 32 + quad * 8;
    f32x4 rp4a = *(const f32x4*)(rp + hbase);
    f32x4 rp4b = *(const f32x4*)(rp + hbase + 4);
    f32x4 ip4a = *(const f32x4*)(ipj + hbase);
    f32x4 ip4b = *(const f32x4*)(ipj + hbase + 4);
    bf16x8 bfr[4];
    #pragma unroll
    for (int ot = 0; ot < 4; ot++)
      bfr[ot] = *(const bf16x8*)(sBF + (((kt * 4 + ot) * 64 + lane) << 3));
    #pragma unroll
    for (int mt = 0; mt < 4; mt++) {
      float q[8];
      #pragma unroll
      for (int j = 0; j < 4; j++) {
        q[j]     = fmaxf(fmaf(Vr[mt], rp4a[j], ur[mt] * ip4a[j]), 0.f);
        q[4 + j] = fmaxf(fmaf(Vr[mt], rp4b[j], ur[mt] * ip4b[j]), 0.f);
      }
      union { bf16x8 v; unsigned w[4]; } a;
      #pragma unroll
      for (int j = 0; j < 4; j++) a.w[j] = pack_bf(q[2 * j], q[2 * j + 1]);
      #pragma unroll
      for (int ot = 0; ot < 4; ot++)
        acc[mt][ot] = __builtin_amdgcn_mfma_f32_16x16x32_bf16(a.v, bfr[ot], acc[mt][ot], 0, 0, 0);
    }
  }
  // C/D layout: col = ot*16 + (lane&15), row = quad*4 + r
  #pragma unroll
  for (int mt = 0; mt < 4; mt++) {
    int rbase = row0 + mt * 16 + quad * 4;
    #pragma unroll
    for (int r = 0; r < 4; r++) {
      #pragma unroll
      for (int ot = 0; ot < 4; ot++)
        wbuf[(size_t)(rbase + r) * O_ + ot * 16 + tl] = f2bf(acc[mt][ot][r]);
    }
  }
}

// ---------------- k_yscan: one wave per (b, 64-t chunk); stage window to LDS, scan.
__global__ __launch_bounds__(64) void k_yscan(const unsigned short* __restrict__ wbuf,
                                              const float* __restrict__ bias,
                                              float* __restrict__ out) {
  __shared__ unsigned short wtile[160 * 64];  // 20 KB
  int b = blockIdx.x;
  int c = blockIdx.y;
  int lane = threadIdx.x;
  int real0 = c * 64;
  int t0 = real0 - 96; if (t0 < 0) t0 = 0;
  int n = real0 + 64 - t0;
  int warm = real0 - t0;

  const uint4* src = (const uint4*)(wbuf + (size_t)(b * S_ + t0) * O_);
  uint4* dst = (uint4*)wtile;
  int total16 = n * 8;
  for (int i = lane; i < total16; i += 64) dst[i] = src[i];
  __syncthreads();

  float y = 0.f;
  float bo = bias[lane];
  float* ob = out + ((size_t)(b * S_ + real0)) * O_ + lane;
  const unsigned short* wl = wtile + lane;
  for (int t = 0; t < n; t++) {
    float wv = bf2f(wl[t * 64]);
    y = fmaf(0.9f, y, 0.1f * wv);
    if (t >= warm) ob[(size_t)(t - warm) * O_] = y + bo;
  }
}

extern "C" void kernel_launch(void* const* d_in, const int* in_sizes, int n_in,
                              void* d_out, int out_size, void* d_ws, size_t ws_size,
                              hipStream_t stream) {
  const float* x   = (const float*)d_in[0];
  const float* ipj = (const float*)d_in[1];
  const float* irc = (const float*)d_in[2];
  const float* rpj = (const float*)d_in[3];
  const float* rrc = (const float*)d_in[4];
  const float* Wr  = (const float*)d_in[5];
  const float* br  = (const float*)d_in[6];
  float* out = (float*)d_out;

  char* ws = (char*)d_ws;
  float* u            = (float*)(ws);                         // 256 KB
  float* V            = (float*)(ws + (256 << 10));           // 256 KB
  unsigned short* BF  = (unsigned short*)(ws + (512 << 10));  // 64 KB
  unsigned short* wbf = (unsigned short*)(ws + (1024 << 10)); // 8 MB

  k_ubf<<<B_ * S_ / 4 + 128, 256, 0, stream>>>(x, irc, Wr, u, BF);
  k_vscan<<<dim3(B_, 64), 64, 0, stream>>>(u, rpj, ipj, rrc, V);
  k_w<<<256, 256, 0, stream>>>(V, u, rpj, ipj, BF, wbf);
  k_yscan<<<dim3(B_, 32), 64, 0, stream>>>(wbf, br, out);
}